// Round 11
// baseline (622.703 us; speedup 1.0000x reference)
//
#include <hip/hip_runtime.h>
#include <hip/hip_bf16.h>
#include <math.h>

// B=4, N=2048, C=384, K=10 per the reference setup.
#define C_DIM 384
#define N_PTS 2048
#define K_NN 10
#define NK (N_PTS * K_NN)
#define LN_EPS_F 1e-5f
#define NB 64                   // x-buckets for three_nn pruning
#define PRUNE_MARGIN 1e-3f

typedef __attribute__((ext_vector_type(8))) short short8v;   // 8 bf16 = 4 VGPR
typedef __attribute__((ext_vector_type(4))) float f32x4;

__device__ __forceinline__ float wave_sum64(float v) {
#pragma unroll
  for (int off = 32; off > 0; off >>= 1) v += __shfl_xor(v, off, 64);
  return v;
}

__device__ __forceinline__ unsigned long long shfl_xor_u64(unsigned long long v, int m) {
  return (unsigned long long)__shfl_xor((long long)v, m, 64);
}

__device__ __forceinline__ unsigned long long quad_shfl_xor_u64(unsigned long long v, int m) {
  return (unsigned long long)__shfl_xor((long long)v, m, 4);
}

__device__ __forceinline__ unsigned short f32_to_bf16_rne(float x) {
  unsigned int u = __float_as_uint(x);
  u += 0x7FFFu + ((u >> 16) & 1u);
  return (unsigned short)(u >> 16);
}

__device__ __forceinline__ unsigned int fkey(float d) {
  unsigned int u = __float_as_uint(d);
  return u ^ (((unsigned int)((int)u >> 31)) | 0x80000000u);
}
__device__ __forceinline__ float funkey(unsigned int t) {
  unsigned int u = (t & 0x80000000u) ? (t ^ 0x80000000u) : ~t;
  return __uint_as_float(u);
}

// frozen exact distance chain (matches all passing rounds bit-for-bit)
#define DIST3(c) __fadd_rn(__fadd_rn(__fmul_rn(-2.f, \
    __fadd_rn(__fadd_rn(__fmul_rn(px, (c).x), __fmul_rn(py, (c).y)), \
              __fmul_rn(pz, (c).z))), ps), (c).w)

// ---------------- conv: q (f32) -> qbf (bf16), 4 elems/thread ----------------------
__global__ __launch_bounds__(256) void conv_q_kernel(
    const float* __restrict__ q, unsigned short* __restrict__ outp) {
  const size_t i = ((size_t)blockIdx.x * 256 + threadIdx.x) * 4;
  float4 v = *reinterpret_cast<const float4*>(&q[i]);
  ushort4 o;
  o.x = f32_to_bf16_rne(v.x); o.y = f32_to_bf16_rne(v.y);
  o.z = f32_to_bf16_rne(v.z); o.w = f32_to_bf16_rne(v.w);
  *reinterpret_cast<ushort4*>(&outp[i]) = o;
}

// ---------- conv: Wk[768][384] (f32) -> WkT bf16, WkT[s*384+n][k] = Wk[s*384+k][n] --
__global__ __launch_bounds__(256) void conv_wkT_kernel(
    const float* __restrict__ Wk, unsigned short* __restrict__ Bt) {
  __shared__ unsigned short tile[64][68];
  const int k0 = blockIdx.x * 64;
  const int sn = blockIdx.y;
  const int s  = sn / 6;
  const int n0 = (sn % 6) * 64;
  const int t = threadIdx.x;
  const int r = t >> 2;
  const int cc = t & 3;
#pragma unroll
  for (int h = 0; h < 4; ++h) {
    const int c = cc * 16 + h * 4;
    float4 v = *reinterpret_cast<const float4*>(
        &Wk[(size_t)(s * 384 + k0 + r) * C_DIM + n0 + c]);
    tile[c + 0][r] = f32_to_bf16_rne(v.x);
    tile[c + 1][r] = f32_to_bf16_rne(v.y);
    tile[c + 2][r] = f32_to_bf16_rne(v.z);
    tile[c + 3][r] = f32_to_bf16_rne(v.w);
  }
  __syncthreads();
#pragma unroll
  for (int h = 0; h < 4; ++h) {
    const int col = cc * 16 + h * 4;
    ushort4 o;
    o.x = tile[r][col + 0]; o.y = tile[r][col + 1];
    o.z = tile[r][col + 2]; o.w = tile[r][col + 3];
    *reinterpret_cast<ushort4*>(
        &Bt[(size_t)(s * 384 + n0 + r) * C_DIM + k0 + col]) = o;
  }
}

// ---------- MFMA bf16 GEMM: qa = q@Wka ; qb = q@Wkb + bk  (value-only path) --------
__global__ __launch_bounds__(64) void mfma_qaqb_kernel(
    const unsigned short* __restrict__ qbf, const unsigned short* __restrict__ Bt,
    const float* __restrict__ bk, float* __restrict__ qa, float* __restrict__ qb) {
  const int lane = threadIdx.x;
  const int bx = blockIdx.x;
  const int seg = bx / 6;
  const int n0 = (bx % 6) * 64;
  const int m0 = blockIdx.y * 64;
  const unsigned short* Bs = Bt + (size_t)seg * C_DIM * C_DIM;
  const int lm = lane & 15;
  const int lk = (lane >> 4) * 8;
  f32x4 acc[4][4] = {};
#pragma unroll 2
  for (int k0 = 0; k0 < C_DIM; k0 += 32) {
    short8v a[4], b[4];
#pragma unroll
    for (int i = 0; i < 4; ++i)
      a[i] = *reinterpret_cast<const short8v*>(
          &qbf[(size_t)(m0 + i * 16 + lm) * C_DIM + k0 + lk]);
#pragma unroll
    for (int j = 0; j < 4; ++j)
      b[j] = *reinterpret_cast<const short8v*>(
          &Bs[(size_t)(n0 + j * 16 + lm) * C_DIM + k0 + lk]);
#pragma unroll
    for (int i = 0; i < 4; ++i)
#pragma unroll
      for (int j = 0; j < 4; ++j)
        acc[i][j] = __builtin_amdgcn_mfma_f32_16x16x32_bf16(a[i], b[j], acc[i][j], 0, 0, 0);
  }
  const int rb = (lane >> 4) * 4;
#pragma unroll
  for (int i = 0; i < 4; ++i)
#pragma unroll
    for (int j = 0; j < 4; ++j) {
      const int c = n0 + j * 16 + lm;
#pragma unroll
      for (int r = 0; r < 4; ++r) {
        const int m = m0 + i * 16 + rb + r;
        float v = acc[i][j][r];
        if (seg == 0) qa[(size_t)m * C_DIM + c] = v;
        else          qb[(size_t)m * C_DIM + c] = v + bk[c];
      }
    }
}

// ---------- f32 GEMM (index-critical): v_off = q@Wv+bv ; hq = q@W1b+b1 -------------
__global__ __launch_bounds__(256) void sgemm_q2_kernel(
    const float* __restrict__ q,
    const float* __restrict__ B0, const float* __restrict__ B1,
    const float* __restrict__ bias0, const float* __restrict__ bias1,
    float* __restrict__ O0, float* __restrict__ O1) {
  __shared__ float As[32][68];
  __shared__ float Bs[32][132];
  const int bx = blockIdx.x;
  const int seg = bx / 3;
  const int n0 = (bx % 3) * 128;
  const int m0 = blockIdx.y * 64;
  const float* Bp = seg ? B1 : B0;
  const float* bp = seg ? bias1 : bias0;
  float* Op = seg ? O1 : O0;
  const int tid = threadIdx.x;
  const int tn = tid & 15;
  const int tm = tid >> 4;
  float acc[4][8] = {};
  for (int k0 = 0; k0 < C_DIM; k0 += 32) {
#pragma unroll
    for (int h = 0; h < 2; ++h) {
      const int idx = tid + h * 256;
      const int r = idx >> 3;
      const int kc = (idx & 7) * 4;
      float4 a4 = *reinterpret_cast<const float4*>(
          &q[(size_t)(m0 + r) * C_DIM + k0 + kc]);
      As[kc + 0][r] = a4.x; As[kc + 1][r] = a4.y;
      As[kc + 2][r] = a4.z; As[kc + 3][r] = a4.w;
    }
#pragma unroll
    for (int h = 0; h < 4; ++h) {
      const int idx = tid + h * 256;
      const int br = idx >> 5;
      const int bc = (idx & 31) * 4;
      float4 b4 = *reinterpret_cast<const float4*>(
          &Bp[(size_t)(k0 + br) * C_DIM + n0 + bc]);
      *reinterpret_cast<float4*>(&Bs[br][bc]) = b4;
    }
    __syncthreads();
#pragma unroll
    for (int kk = 0; kk < 32; ++kk) {
      float4 a4 = *reinterpret_cast<const float4*>(&As[kk][tm << 2]);
      float4 b0 = *reinterpret_cast<const float4*>(&Bs[kk][tn << 2]);
      float4 b1 = *reinterpret_cast<const float4*>(&Bs[kk][(tn << 2) + 64]);
      float av[4] = {a4.x, a4.y, a4.z, a4.w};
      float bw[8] = {b0.x, b0.y, b0.z, b0.w, b1.x, b1.y, b1.z, b1.w};
#pragma unroll
      for (int i = 0; i < 4; ++i)
#pragma unroll
        for (int j = 0; j < 8; ++j) acc[i][j] = fmaf(av[i], bw[j], acc[i][j]);
    }
    __syncthreads();
  }
#pragma unroll
  for (int i = 0; i < 4; ++i) {
    const int m = m0 + (tm << 2) + i;
    const int c0 = n0 + (tn << 2);
    float4 o0, o1;
    o0.x = acc[i][0]; o0.y = acc[i][1]; o0.z = acc[i][2]; o0.w = acc[i][3];
    o1.x = acc[i][4]; o1.y = acc[i][5]; o1.z = acc[i][6]; o1.w = acc[i][7];
    if (bp) {
      o0.x += bp[c0 + 0]; o0.y += bp[c0 + 1]; o0.z += bp[c0 + 2]; o0.w += bp[c0 + 3];
      o1.x += bp[c0 + 64]; o1.y += bp[c0 + 65]; o1.z += bp[c0 + 66]; o1.w += bp[c0 + 67];
    }
    *reinterpret_cast<float4*>(&Op[(size_t)m * C_DIM + c0]) = o0;
    *reinterpret_cast<float4*>(&Op[(size_t)m * C_DIM + c0 + 64]) = o1;
  }
}

// ---------- hv GEMM: 64x64 tiles, 768 blocks (round-2 proven form) -----------------
__global__ __launch_bounds__(256) void gemm384_kernel(
    const float* __restrict__ A, const float* __restrict__ W,
    const float* __restrict__ bias, float* __restrict__ Out) {
  __shared__ float As[32][64];
  __shared__ float Bs[32][64];
  const int bm = blockIdx.y * 64;
  const int bn = blockIdx.x * 64;
  const int tid = threadIdx.x;
  const int tx = tid & 15;
  const int ty = tid >> 4;
  const int arow = tid >> 3;
  const int akc  = (tid & 7) << 2;
  const int brow = tid >> 4;
  const int bnc  = (tid & 15) << 2;
  float acc[4][4] = {{0.f, 0.f, 0.f, 0.f}, {0.f, 0.f, 0.f, 0.f},
                     {0.f, 0.f, 0.f, 0.f}, {0.f, 0.f, 0.f, 0.f}};
  for (int k0 = 0; k0 < C_DIM; k0 += 32) {
#pragma unroll
    for (int h = 0; h < 2; ++h) {
      float4 a4 = *reinterpret_cast<const float4*>(
          &A[(size_t)(bm + arow + h * 32) * C_DIM + k0 + akc]);
      As[akc + 0][arow + h * 32] = a4.x;
      As[akc + 1][arow + h * 32] = a4.y;
      As[akc + 2][arow + h * 32] = a4.z;
      As[akc + 3][arow + h * 32] = a4.w;
      float4 b4 = *reinterpret_cast<const float4*>(
          &W[(size_t)(k0 + brow + h * 16) * C_DIM + bn + bnc]);
      *reinterpret_cast<float4*>(&Bs[brow + h * 16][bnc]) = b4;
    }
    __syncthreads();
#pragma unroll
    for (int k = 0; k < 32; ++k) {
      float4 a4 = *reinterpret_cast<const float4*>(&As[k][ty << 2]);
      float4 b4 = *reinterpret_cast<const float4*>(&Bs[k][tx << 2]);
      float av[4] = {a4.x, a4.y, a4.z, a4.w};
      float bw[4] = {b4.x, b4.y, b4.z, b4.w};
#pragma unroll
      for (int i = 0; i < 4; ++i)
#pragma unroll
        for (int j = 0; j < 4; ++j) acc[i][j] = fmaf(av[i], bw[j], acc[i][j]);
    }
    __syncthreads();
  }
#pragma unroll
  for (int i = 0; i < 4; ++i) {
    const int m = bm + (ty << 2) + i;
    const int n0 = bn + (tx << 2);
    float4 o;
    o.x = acc[i][0]; o.y = acc[i][1]; o.z = acc[i][2]; o.w = acc[i][3];
    if (bias) {
      o.x += bias[n0 + 0]; o.y += bias[n0 + 1];
      o.z += bias[n0 + 2]; o.w += bias[n0 + 3];
    }
    *reinterpret_cast<float4*>(&Out[(size_t)m * C_DIM + n0]) = o;
  }
}

// ------------- kNN: one wave per query, exact lexicographic (d, idx) top-10 -------
__global__ __launch_bounds__(256) void knn_wave_kernel(
    const float* __restrict__ q_pos, int* __restrict__ idx_out,
    float* __restrict__ scale_out) {
  const int wid = threadIdx.x >> 6;
  const int lane = threadIdx.x & 63;
  const int q = blockIdx.x * 4 + wid;
  const int b = q >> 11;
  const int qi = q & 2047;
  __shared__ float4 sc[N_PTS];
  const float* P = q_pos + (size_t)b * N_PTS * 3;
  for (int i = threadIdx.x; i < N_PTS; i += 256) {
    float x = P[i * 3 + 0], y = P[i * 3 + 1], z = P[i * 3 + 2];
    float s = __fadd_rn(__fadd_rn(__fmul_rn(x, x), __fmul_rn(y, y)), __fmul_rn(z, z));
    sc[i] = make_float4(x, y, z, s);
  }
  __syncthreads();
  const float4 qc = sc[qi];
  unsigned long long bd[K_NN];
#pragma unroll
  for (int t = 0; t < K_NN; ++t) bd[t] = ~0ull;
  for (int t = 0; t < N_PTS / 64; ++t) {
    const int j = (t << 6) + lane;
    float4 c = sc[j];
    float dot = __fadd_rn(__fadd_rn(__fmul_rn(qc.x, c.x), __fmul_rn(qc.y, c.y)),
                          __fmul_rn(qc.z, c.z));
    float d = __fadd_rn(__fadd_rn(__fmul_rn(-2.f, dot), qc.w), c.w);
    unsigned long long v = ((unsigned long long)fkey(d) << 32) | (unsigned int)j;
    if (v < bd[K_NN - 1]) {
#pragma unroll
      for (int r = 0; r < K_NN; ++r) {
        bool lt = bd[r] < v;
        unsigned long long lo = lt ? bd[r] : v;
        unsigned long long hi = lt ? v : bd[r];
        bd[r] = lo; v = hi;
      }
    }
  }
  unsigned long long cur = bd[0];
  unsigned long long mine = 0;
#pragma unroll
  for (int r = 0; r < K_NN; ++r) {
    unsigned long long m = cur;
#pragma unroll
    for (int off = 32; off >= 1; off >>= 1) {
      unsigned long long o = shfl_xor_u64(m, off);
      m = (o < m) ? o : m;
    }
    if (cur == m) {
      cur = bd[1];
#pragma unroll
      for (int s = 1; s < K_NN - 1; ++s) bd[s] = bd[s + 1];
      bd[K_NN - 1] = ~0ull;
    }
    if (lane == r) mine = m;
  }
  const int nidx = (int)(mine & 0xFFFFFFFFull);
  if (lane < K_NN) idx_out[(size_t)q * K_NN + lane] = nidx;
  float mnx, mny, mnz, mxx, mxy, mxz;
  if (lane < K_NN) {
    float4 c = sc[nidx];
    mnx = c.x; mny = c.y; mnz = c.z; mxx = c.x; mxy = c.y; mxz = c.z;
  } else {
    mnx = 1e30f; mny = 1e30f; mnz = 1e30f;
    mxx = -1e30f; mxy = -1e30f; mxz = -1e30f;
  }
#pragma unroll
  for (int off = 32; off >= 1; off >>= 1) {
    mnx = fminf(mnx, __shfl_xor(mnx, off, 64));
    mny = fminf(mny, __shfl_xor(mny, off, 64));
    mnz = fminf(mnz, __shfl_xor(mnz, off, 64));
    mxx = fmaxf(mxx, __shfl_xor(mxx, off, 64));
    mxy = fmaxf(mxy, __shfl_xor(mxy, off, 64));
    mxz = fmaxf(mxz, __shfl_xor(mxz, off, 64));
  }
  if (lane == 0) {
    scale_out[(size_t)q * 3 + 0] = (mxx - mnx) * 0.5f;
    scale_out[(size_t)q * 3 + 1] = (mxy - mny) * 0.5f;
    scale_out[(size_t)q * 3 + 2] = (mxz - mnz) * 0.5f;
  }
}

// -------- per (b,n,k): h=hv[g]+hq -> LN -> GELU -> @W2 -> tanh -> shift_pos --------
__global__ __launch_bounds__(256) void mid_kernel(
    const float* __restrict__ hv, const float* __restrict__ hq,
    const int* __restrict__ idx, const float* __restrict__ scale,
    const float* __restrict__ q_pos, const float* __restrict__ ln_g,
    const float* __restrict__ ln_b, const float* __restrict__ W2,
    float* __restrict__ shift_pos) {
  const int wid = threadIdx.x >> 6;
  const int lane = threadIdx.x & 63;
  const long row = (long)blockIdx.x * 4 + wid;
  const long bn = row / K_NN;
  const int b = (int)(bn / N_PTS);
  const int g = idx[row];
  const float* hvp = hv + ((size_t)b * N_PTS + g) * C_DIM;
  const float* hqp = hq + (size_t)bn * C_DIM;
  float h[6];
  float s = 0.f;
#pragma unroll
  for (int r = 0; r < 6; ++r) {
    h[r] = hvp[lane + (r << 6)] + hqp[lane + (r << 6)];
    s += h[r];
  }
  s = wave_sum64(s);
  const float mu = s / 384.f;
  float hc[6];
  float vs = 0.f;
#pragma unroll
  for (int r = 0; r < 6; ++r) { hc[r] = h[r] - mu; vs += hc[r] * hc[r]; }
  vs = wave_sum64(vs);
  const float inv = 1.f / sqrtf(vs / 384.f + LN_EPS_F);
  float o0 = 0.f, o1 = 0.f, o2 = 0.f;
#pragma unroll
  for (int r = 0; r < 6; ++r) {
    const int c = lane + (r << 6);
    float y = hc[r] * inv * ln_g[c] + ln_b[c];
    float ge = 0.5f * y * (1.f + erff(y * 0.70710678118654752f));
    o0 += ge * W2[c * 3 + 0];
    o1 += ge * W2[c * 3 + 1];
    o2 += ge * W2[c * 3 + 2];
  }
  o0 = wave_sum64(o0); o1 = wave_sum64(o1); o2 = wave_sum64(o2);
  if (lane < 3) {
    float o = (lane == 0) ? o0 : ((lane == 1) ? o1 : o2);
    float off = tanhf(o);
    float lv = q_pos[((size_t)b * N_PTS + g) * 3 + lane];
    float sc = scale[(size_t)bn * 3 + lane];
    shift_pos[(size_t)row * 3 + lane] = lv + off * sc;
  }
}

// ---------- bucket candidates by x (per batch); also zero the query histogram ------
__global__ __launch_bounds__(256) void bucket_cand_kernel(
    const float* __restrict__ q_pos, float4* __restrict__ cbuf,
    unsigned short* __restrict__ cidx, int* __restrict__ cstart,
    float4* __restrict__ crange, int* __restrict__ qhist) {
  const int b = blockIdx.x;
  const float* P = q_pos + (size_t)b * N_PTS * 3;
  const int tid = threadIdx.x;
  if (tid < NB) qhist[b * NB + tid] = 0;
  __shared__ float redmn[4], redmx[4];
  __shared__ float sxmin, sinvw;
  __shared__ int hist[NB], offs[NB + 1], curp[NB];
  float mn = 1e30f, mx = -1e30f;
  for (int i = tid; i < N_PTS; i += 256) {
    float x = P[i * 3];
    mn = fminf(mn, x); mx = fmaxf(mx, x);
  }
#pragma unroll
  for (int off = 32; off >= 1; off >>= 1) {
    mn = fminf(mn, __shfl_xor(mn, off, 64));
    mx = fmaxf(mx, __shfl_xor(mx, off, 64));
  }
  if ((tid & 63) == 0) { redmn[tid >> 6] = mn; redmx[tid >> 6] = mx; }
  if (tid < NB) hist[tid] = 0;
  __syncthreads();
  if (tid == 0) {
    float a = fminf(fminf(redmn[0], redmn[1]), fminf(redmn[2], redmn[3]));
    float c = fmaxf(fmaxf(redmx[0], redmx[1]), fmaxf(redmx[2], redmx[3]));
    float wd = (c - a) / (float)NB;
    sxmin = a;
    sinvw = (wd > 0.f) ? 1.f / wd : 0.f;
    crange[b] = make_float4(a, wd, sinvw, 0.f);
  }
  __syncthreads();
  const float xmin = sxmin, invw = sinvw;
  for (int i = tid; i < N_PTS; i += 256) {
    int bk = min(NB - 1, max(0, (int)((P[i * 3] - xmin) * invw)));
    atomicAdd(&hist[bk], 1);
  }
  __syncthreads();
  if (tid == 0) {
    int a = 0;
    for (int k = 0; k < NB; ++k) { offs[k] = a; a += hist[k]; }
    offs[NB] = a;
  }
  __syncthreads();
  if (tid < NB) curp[tid] = offs[tid];
  if (tid <= NB) cstart[b * (NB + 1) + tid] = offs[tid];
  __syncthreads();
  for (int i = tid; i < N_PTS; i += 256) {
    float x = P[i * 3 + 0], y = P[i * 3 + 1], z = P[i * 3 + 2];
    int bk = min(NB - 1, max(0, (int)((x - xmin) * invw)));
    int p = atomicAdd(&curp[bk], 1);
    float ss = __fadd_rn(__fadd_rn(__fmul_rn(x, x), __fmul_rn(y, y)), __fmul_rn(z, z));
    cbuf[(size_t)b * N_PTS + p] = make_float4(x, y, z, ss);
    cidx[(size_t)b * N_PTS + p] = (unsigned short)i;
  }
}

// ---------- query sort by (batch, x-bucket): count -> scan -> scatter --------------
__global__ __launch_bounds__(256) void qcount_kernel(
    const float* __restrict__ shift_pos, const float4* __restrict__ crange,
    int* __restrict__ qhist) {
  const long jq = (long)blockIdx.x * 256 + threadIdx.x;
  const int b = (int)(jq / NK);
  const float4 rg = crange[b];
  const float px = shift_pos[(size_t)jq * 3];
  const int bk = min(NB - 1, max(0, (int)((px - rg.x) * rg.z)));
  atomicAdd(&qhist[b * NB + bk], 1);
}

__global__ __launch_bounds__(256) void qscan_kernel(
    const int* __restrict__ qhist, int* __restrict__ qcur) {
  __shared__ int h[256];
  __shared__ int pre[256];
  const int tid = threadIdx.x;
  h[tid] = qhist[tid];
  __syncthreads();
  if (tid == 0) {
    int a = 0;
    for (int i = 0; i < 256; ++i) { pre[i] = a; a += h[i]; }
  }
  __syncthreads();
  qcur[tid] = pre[tid];
}

__global__ __launch_bounds__(256) void qscatter_kernel(
    const float* __restrict__ shift_pos, const float4* __restrict__ crange,
    int* __restrict__ qcur, int* __restrict__ qorder) {
  const long jq = (long)blockIdx.x * 256 + threadIdx.x;
  const int b = (int)(jq / NK);
  const float4 rg = crange[b];
  const float px = shift_pos[(size_t)jq * 3];
  const int bk = min(NB - 1, max(0, (int)((px - rg.x) * rg.z)));
  const int pos = atomicAdd(&qcur[b * NB + bk], 1);
  qorder[pos] = (int)jq;
}

// ---------- three_nn, quad-lane pruned scan on bucket-sorted queries ---------------
// 4 lanes per query: lane r scans candidates start+r, +4 of each bucket with a
// private packed-u64 (fkey(d), idx) top-3. Prune bound d^ = quad-min of per-lane
// t2: each lane's 3rd-best-of-subset >= global d2, so d^ >= d2_true => pruning
// stays conservative (same margin argument as rounds 9/10). Expansion decisions
// depend only on (px, d^) -> quad-uniform, lanes stay converged. Final merge:
// width-4 butterfly inserting the partner's sorted triple (disjoint subsets =>
// exact lexicographic top-3 of the union => deterministic, sort-order invariant).
__global__ __launch_bounds__(256) void three_nn_quad_kernel(
    const float* __restrict__ shift_pos, const float4* __restrict__ cbuf,
    const unsigned short* __restrict__ cidx, const int* __restrict__ cstart,
    const float4* __restrict__ crange, const int* __restrict__ qorder,
    int* __restrict__ idx3, float* __restrict__ w3) {
  const int tid = threadIdx.x;
  const int b = blockIdx.x / (NK / 64);   // 320 blocks per batch, never straddles
  const int qslot = blockIdx.x * 64 + (tid >> 2);
  const int sub = tid & 3;
  __shared__ float4 sc[N_PTS];
  __shared__ unsigned short sid[N_PTS];
  __shared__ int sstart[NB + 1];
  for (int i = tid; i < N_PTS; i += 256) {
    sc[i] = cbuf[(size_t)b * N_PTS + i];
    sid[i] = cidx[(size_t)b * N_PTS + i];
  }
  if (tid <= NB) sstart[tid] = cstart[b * (NB + 1) + tid];
  __syncthreads();
  const int jq = qorder[qslot];
  const float* S = shift_pos + (size_t)jq * 3;
  const float px = S[0], py = S[1], pz = S[2];
  const float ps = __fadd_rn(__fadd_rn(__fmul_rn(px, px), __fmul_rn(py, py)),
                             __fmul_rn(pz, pz));
  const float4 rg = crange[b];
  const float xmin = rg.x, w = rg.y, invw = rg.z;
  const int myb = min(NB - 1, max(0, (int)((px - xmin) * invw)));
  unsigned long long t0 = ~0ull, t1 = ~0ull, t2 = ~0ull;
  auto ins64 = [&](unsigned long long v) {
    if (v < t2) {
      if (v < t0) { t2 = t1; t1 = t0; t0 = v; }
      else if (v < t1) { t2 = t1; t1 = v; }
      else t2 = v;
    }
  };
  auto scanb = [&](int bb) {
    const int pe = sstart[bb + 1];
    for (int p = sstart[bb] + sub; p < pe; p += 4) {
      float4 c = sc[p];
      float d = DIST3(c);
      ins64(((unsigned long long)fkey(d) << 32) | (unsigned int)sid[p]);
    }
  };
  auto d2hat = [&]() -> float {
    unsigned long long m = t2;
    unsigned long long o = quad_shfl_xor_u64(m, 1); m = (o < m) ? o : m;
    o = quad_shfl_xor_u64(m, 2); m = (o < m) ? o : m;
    unsigned int k = (unsigned int)(m >> 32);
    return (k == 0xFFFFFFFFu) ? 1e30f : funkey(k);
  };
  scanb(myb);
  int bl = myb - 1, br = myb + 1;
  while (bl >= 0 || br < NB) {
    bool prog = false;
    float dh = d2hat();
    if (bl >= 0) {
      float gap = px - (xmin + (float)(bl + 1) * w);
      if (__fmul_rn(gap, gap) <= dh + PRUNE_MARGIN) { scanb(bl); --bl; prog = true; }
      else bl = -1;
    }
    dh = d2hat();
    if (br < NB) {
      float gap = (xmin + (float)br * w) - px;
      if (__fmul_rn(gap, gap) <= dh + PRUNE_MARGIN) { scanb(br); ++br; prog = true; }
      else br = NB;
    }
    if (!prog) break;
  }
  // exact quad merge: butterfly over sub-lane masks 1,2 (disjoint candidate sets)
#pragma unroll
  for (int mask = 1; mask <= 2; mask <<= 1) {
    unsigned long long o0 = quad_shfl_xor_u64(t0, mask);
    unsigned long long o1 = quad_shfl_xor_u64(t1, mask);
    unsigned long long o2 = quad_shfl_xor_u64(t2, mask);
    ins64(o0); ins64(o1); ins64(o2);
  }
  if (sub == 0) {
    const float d0 = funkey((unsigned int)(t0 >> 32));
    const float d1 = funkey((unsigned int)(t1 >> 32));
    const float d2v = funkey((unsigned int)(t2 >> 32));
    const int i0 = (int)(unsigned int)(t0 & 0xFFFFFFFFull);
    const int i1 = (int)(unsigned int)(t1 & 0xFFFFFFFFull);
    const int i2 = (int)(unsigned int)(t2 & 0xFFFFFFFFull);
    const float r0 = 1.f / (d0 + 1e-8f);
    const float r1 = 1.f / (d1 + 1e-8f);
    const float r2 = 1.f / (d2v + 1e-8f);
    const float rs = (r0 + r1) + r2;
    const size_t ob = (size_t)jq * 3;
    idx3[ob + 0] = i0; idx3[ob + 1] = i1; idx3[ob + 2] = i2;
    w3[ob + 0] = r0 / rs; w3[ob + 1] = r1 / rs; w3[ob + 2] = r2 / rs;
  }
}

// -------- final: out[bn,c] = max_k leaky( sum_i w_i*qa[idx3_i,c] + qb-qa ) --------
__global__ __launch_bounds__(256) void final_kernel(
    const float* __restrict__ qa, const float* __restrict__ qb,
    const int* __restrict__ idx3, const float* __restrict__ w3,
    float* __restrict__ out) {
  const int wid = threadIdx.x >> 6;
  const int lane = threadIdx.x & 63;
  const long bn = (long)blockIdx.x * 4 + wid;
  const int b = (int)(bn / N_PTS);
  const float* qaB = qa + (size_t)b * N_PTS * C_DIM;
  float base[6], mx[6];
#pragma unroll
  for (int r = 0; r < 6; ++r) {
    const size_t c = (size_t)bn * C_DIM + lane + (r << 6);
    base[r] = qb[c] - qa[c];
    mx[r] = -1e30f;
  }
  const size_t kb = (size_t)bn * K_NN * 3;
  for (int k = 0; k < K_NN; ++k) {
    const int a0 = idx3[kb + k * 3 + 0];
    const int a1 = idx3[kb + k * 3 + 1];
    const int a2 = idx3[kb + k * 3 + 2];
    const float w0 = w3[kb + k * 3 + 0];
    const float w1 = w3[kb + k * 3 + 1];
    const float w2c = w3[kb + k * 3 + 2];
    const float* p0 = qaB + (size_t)a0 * C_DIM;
    const float* p1 = qaB + (size_t)a1 * C_DIM;
    const float* p2 = qaB + (size_t)a2 * C_DIM;
#pragma unroll
    for (int r = 0; r < 6; ++r) {
      const int c = lane + (r << 6);
      float v = w0 * p0[c] + w1 * p1[c] + w2c * p2[c] + base[r];
      v = (v >= 0.f) ? v : 0.2f * v;
      mx[r] = fmaxf(mx[r], v);
    }
  }
#pragma unroll
  for (int r = 0; r < 6; ++r)
    out[(size_t)bn * C_DIM + lane + (r << 6)] = mx[r];
}

extern "C" void kernel_launch(void* const* d_in, const int* in_sizes, int n_in,
                              void* d_out, int out_size, void* d_ws, size_t ws_size,
                              hipStream_t stream) {
  const float* q     = (const float*)d_in[0];
  const float* q_pos = (const float*)d_in[1];
  const float* Wv    = (const float*)d_in[2];
  const float* bv    = (const float*)d_in[3];
  const float* W1    = (const float*)d_in[4];
  const float* b1    = (const float*)d_in[5];
  const float* ln_g  = (const float*)d_in[6];
  const float* ln_b  = (const float*)d_in[7];
  const float* W2    = (const float*)d_in[8];
  const float* Wk    = (const float*)d_in[9];
  const float* bk    = (const float*)d_in[10];
  float* out = (float*)d_out;

  const int BN = in_sizes[0] / C_DIM;  // B*N = 8192
  const int B  = BN / N_PTS;           // 4

  const size_t BNC = (size_t)BN * C_DIM;
  float* ws = (float*)d_ws;
  float* bufA = ws;              // qa
  float* bufB = bufA + BNC;      // qbf -> hv -> bucket/sort structures
  float* bufC = bufB + BNC;      // WkT -> hq
  float* bufD = bufC + BNC;      // qb
  float* shift = bufD + BNC;                       // BN*K*3
  float* scale = shift + (size_t)BN * K_NN * 3;    // BN*3
  float* w3    = scale + (size_t)BN * 3;           // BN*K*3
  int*   idx   = (int*)(w3 + (size_t)BN * K_NN * 3);  // BN*K
  int*   idx3  = idx + (size_t)BN * K_NN;             // BN*K*3

  float* v_off = out;            // d_out staging: dead until final_kernel rewrites it
  unsigned short* qbf = (unsigned short*)bufB;   // 8192x384 bf16
  unsigned short* WkT = (unsigned short*)bufC;   // 768x384 bf16

  // bucket/sort structures alias bufB (hv dead after mid_kernel). Float offsets:
  // cbuf 32768 | cidx 4096 (u16 x8192 = 16KB) | cstart 260 | crange 16 |
  // qorder 81920 | qhist 256 | qcur 256. Total 119572 << BNC.
  float4* cbuf = (float4*)bufB;
  unsigned short* cidx = (unsigned short*)(bufB + 32768);
  int* cstartp = (int*)(bufB + 32768 + 4096);
  float4* crange = (float4*)(bufB + 37124);               // byte 148496 %16==0
  int* qorder = (int*)(bufB + 37140);
  int* qhist  = (int*)(bufB + 37140 + 81920);
  int* qcur   = (int*)(bufB + 37140 + 81920 + 256);

  // 1) conversions (value-only path inputs)
  conv_q_kernel<<<(BN * C_DIM) / 1024, 256, 0, stream>>>(q, qbf);
  conv_wkT_kernel<<<dim3(6, 12), 256, 0, stream>>>(Wk, WkT);
  // 2) kNN (wave per query) -> idx, scale
  knn_wave_kernel<<<BN / 4, 256, 0, stream>>>(q_pos, idx, scale);
  // 3) MFMA bf16: qa = q@Wka ; qb = q@Wkb + bk
  mfma_qaqb_kernel<<<dim3(12, BN / 64), 64, 0, stream>>>(qbf, WkT, bk, bufA, bufD);
  // 4) f32 exact: v_off = q@Wv+bv (d_out) ; hq = q@W1b+b1 (bufC, overwrites WkT)
  sgemm_q2_kernel<<<dim3(6, BN / 64), 256, 0, stream>>>(
      q, Wv, W1 + (size_t)C_DIM * C_DIM, bv, b1, v_off, bufC);
  // 5) hv = v_off @ W1a (bufB, overwrites qbf)
  gemm384_kernel<<<dim3(C_DIM / 64, BN / 64), 256, 0, stream>>>(v_off, W1, nullptr, bufB);
  // 6) mid: LN/GELU/W2/tanh -> shift_pos
  mid_kernel<<<(BN * K_NN) / 4, 256, 0, stream>>>(bufB, bufC, idx, scale, q_pos,
                                                  ln_g, ln_b, W2, shift);
  // 7) candidate buckets (bufB free now) + query sort + quad-lane pruned three_nn
  bucket_cand_kernel<<<B, 256, 0, stream>>>(q_pos, cbuf, cidx, cstartp, crange, qhist);
  qcount_kernel<<<(BN * K_NN) / 256, 256, 0, stream>>>(shift, crange, qhist);
  qscan_kernel<<<1, 256, 0, stream>>>(qhist, qcur);
  qscatter_kernel<<<(BN * K_NN) / 256, 256, 0, stream>>>(shift, crange, qcur, qorder);
  three_nn_quad_kernel<<<(BN * K_NN) / 64, 256, 0, stream>>>(
      shift, cbuf, cidx, cstartp, crange, qorder, idx3, w3);
  // 8) final gather + leaky + max
  final_kernel<<<BN / 4, 256, 0, stream>>>(bufA, bufD, idx3, w3, out);
}

// Round 12
// 355.556 us; speedup vs baseline: 1.7513x; 1.7513x over previous
//
#include <hip/hip_runtime.h>
#include <hip/hip_bf16.h>
#include <math.h>

// B=4, N=2048, C=384, K=10 per the reference setup.
#define C_DIM 384
#define N_PTS 2048
#define K_NN 10
#define NK (N_PTS * K_NN)
#define LN_EPS_F 1e-5f

#define TCC 8                   // three_nn candidate chunks
#define TCHUNK (N_PTS / TCC)    // 256

typedef __attribute__((ext_vector_type(8))) short short8v;   // 8 bf16 = 4 VGPR
typedef __attribute__((ext_vector_type(4))) float f32x4;

__device__ __forceinline__ float wave_sum64(float v) {
#pragma unroll
  for (int off = 32; off > 0; off >>= 1) v += __shfl_xor(v, off, 64);
  return v;
}

__device__ __forceinline__ unsigned long long shfl_xor_u64(unsigned long long v, int m) {
  return (unsigned long long)__shfl_xor((long long)v, m, 64);
}

__device__ __forceinline__ unsigned short f32_to_bf16_rne(float x) {
  unsigned int u = __float_as_uint(x);
  u += 0x7FFFu + ((u >> 16) & 1u);
  return (unsigned short)(u >> 16);
}

// ---------------- conv: q (f32) -> qbf (bf16), 4 elems/thread ----------------------
__global__ __launch_bounds__(256) void conv_q_kernel(
    const float* __restrict__ q, unsigned short* __restrict__ outp) {
  const size_t i = ((size_t)blockIdx.x * 256 + threadIdx.x) * 4;
  float4 v = *reinterpret_cast<const float4*>(&q[i]);
  ushort4 o;
  o.x = f32_to_bf16_rne(v.x); o.y = f32_to_bf16_rne(v.y);
  o.z = f32_to_bf16_rne(v.z); o.w = f32_to_bf16_rne(v.w);
  *reinterpret_cast<ushort4*>(&outp[i]) = o;
}

// ---------- conv: Wk[768][384] (f32) -> WkT bf16, WkT[s*384+n][k] = Wk[s*384+k][n] --
__global__ __launch_bounds__(256) void conv_wkT_kernel(
    const float* __restrict__ Wk, unsigned short* __restrict__ Bt) {
  __shared__ unsigned short tile[64][68];
  const int k0 = blockIdx.x * 64;       // 0..320
  const int sn = blockIdx.y;            // 0..11
  const int s  = sn / 6;
  const int n0 = (sn % 6) * 64;
  const int t = threadIdx.x;
  const int r = t >> 2;                 // 0..63
  const int cc = t & 3;
#pragma unroll
  for (int h = 0; h < 4; ++h) {
    const int c = cc * 16 + h * 4;
    float4 v = *reinterpret_cast<const float4*>(
        &Wk[(size_t)(s * 384 + k0 + r) * C_DIM + n0 + c]);
    tile[c + 0][r] = f32_to_bf16_rne(v.x);
    tile[c + 1][r] = f32_to_bf16_rne(v.y);
    tile[c + 2][r] = f32_to_bf16_rne(v.z);
    tile[c + 3][r] = f32_to_bf16_rne(v.w);
  }
  __syncthreads();
#pragma unroll
  for (int h = 0; h < 4; ++h) {
    const int col = cc * 16 + h * 4;
    ushort4 o;
    o.x = tile[r][col + 0]; o.y = tile[r][col + 1];
    o.z = tile[r][col + 2]; o.w = tile[r][col + 3];
    *reinterpret_cast<ushort4*>(
        &Bt[(size_t)(s * 384 + n0 + r) * C_DIM + k0 + col]) = o;
  }
}

// ---------- MFMA bf16 GEMM: qa = q@Wka ; qb = q@Wkb + bk  (value-only path) --------
// 1 wave per block, 64x64 output tile; frags straight from global (L2-hot).
// A frag: lane l holds A[row = l&15][k = (l>>4)*8 + e]; B frag (from WkT[n][k]):
// lane l holds B[k = (l>>4)*8 + e][col = l&15]. C: col = l&15, row = (l>>4)*4 + r.
__global__ __launch_bounds__(64) void mfma_qaqb_kernel(
    const unsigned short* __restrict__ qbf, const unsigned short* __restrict__ Bt,
    const float* __restrict__ bk, float* __restrict__ qa, float* __restrict__ qb) {
  const int lane = threadIdx.x;
  const int bx = blockIdx.x;            // 0..11
  const int seg = bx / 6;
  const int n0 = (bx % 6) * 64;
  const int m0 = blockIdx.y * 64;
  const unsigned short* Bs = Bt + (size_t)seg * C_DIM * C_DIM;
  const int lm = lane & 15;
  const int lk = (lane >> 4) * 8;
  f32x4 acc[4][4] = {};
#pragma unroll 2
  for (int k0 = 0; k0 < C_DIM; k0 += 32) {
    short8v a[4], b[4];
#pragma unroll
    for (int i = 0; i < 4; ++i)
      a[i] = *reinterpret_cast<const short8v*>(
          &qbf[(size_t)(m0 + i * 16 + lm) * C_DIM + k0 + lk]);
#pragma unroll
    for (int j = 0; j < 4; ++j)
      b[j] = *reinterpret_cast<const short8v*>(
          &Bs[(size_t)(n0 + j * 16 + lm) * C_DIM + k0 + lk]);
#pragma unroll
    for (int i = 0; i < 4; ++i)
#pragma unroll
      for (int j = 0; j < 4; ++j)
        acc[i][j] = __builtin_amdgcn_mfma_f32_16x16x32_bf16(a[i], b[j], acc[i][j], 0, 0, 0);
  }
  const int rb = (lane >> 4) * 4;
#pragma unroll
  for (int i = 0; i < 4; ++i)
#pragma unroll
    for (int j = 0; j < 4; ++j) {
      const int c = n0 + j * 16 + lm;
#pragma unroll
      for (int r = 0; r < 4; ++r) {
        const int m = m0 + i * 16 + rb + r;
        float v = acc[i][j][r];
        if (seg == 0) qa[(size_t)m * C_DIM + c] = v;
        else          qb[(size_t)m * C_DIM + c] = v + bk[c];
      }
    }
}

// ---------- f32 GEMM (index-critical): v_off = q@Wv+bv ; hq = q@W1b+b1 -------------
// BM=64, BN=128 -> 768 blocks. Per-element ascending-k fmaf chain: bit-identical
// to all prior passing rounds (feeds argmin downstream — frozen).
__global__ __launch_bounds__(256) void sgemm_q2_kernel(
    const float* __restrict__ q,
    const float* __restrict__ B0, const float* __restrict__ B1,
    const float* __restrict__ bias0, const float* __restrict__ bias1,
    float* __restrict__ O0, float* __restrict__ O1) {
  __shared__ float As[32][68];
  __shared__ float Bs[32][132];
  const int bx = blockIdx.x;            // 0..5
  const int seg = bx / 3;
  const int n0 = (bx % 3) * 128;
  const int m0 = blockIdx.y * 64;
  const float* Bp = seg ? B1 : B0;
  const float* bp = seg ? bias1 : bias0;
  float* Op = seg ? O1 : O0;
  const int tid = threadIdx.x;
  const int tn = tid & 15;
  const int tm = tid >> 4;
  float acc[4][8] = {};
  for (int k0 = 0; k0 < C_DIM; k0 += 32) {
#pragma unroll
    for (int h = 0; h < 2; ++h) {
      const int idx = tid + h * 256;
      const int r = idx >> 3;           // 0..63
      const int kc = (idx & 7) * 4;     // 0..28
      float4 a4 = *reinterpret_cast<const float4*>(
          &q[(size_t)(m0 + r) * C_DIM + k0 + kc]);
      As[kc + 0][r] = a4.x; As[kc + 1][r] = a4.y;
      As[kc + 2][r] = a4.z; As[kc + 3][r] = a4.w;
    }
#pragma unroll
    for (int h = 0; h < 4; ++h) {
      const int idx = tid + h * 256;
      const int br = idx >> 5;          // 0..31
      const int bc = (idx & 31) * 4;    // 0..124
      float4 b4 = *reinterpret_cast<const float4*>(
          &Bp[(size_t)(k0 + br) * C_DIM + n0 + bc]);
      *reinterpret_cast<float4*>(&Bs[br][bc]) = b4;
    }
    __syncthreads();
#pragma unroll
    for (int kk = 0; kk < 32; ++kk) {
      float4 a4 = *reinterpret_cast<const float4*>(&As[kk][tm << 2]);
      float4 b0 = *reinterpret_cast<const float4*>(&Bs[kk][tn << 2]);
      float4 b1 = *reinterpret_cast<const float4*>(&Bs[kk][(tn << 2) + 64]);
      float av[4] = {a4.x, a4.y, a4.z, a4.w};
      float bw[8] = {b0.x, b0.y, b0.z, b0.w, b1.x, b1.y, b1.z, b1.w};
#pragma unroll
      for (int i = 0; i < 4; ++i)
#pragma unroll
        for (int j = 0; j < 8; ++j) acc[i][j] = fmaf(av[i], bw[j], acc[i][j]);
    }
    __syncthreads();
  }
#pragma unroll
  for (int i = 0; i < 4; ++i) {
    const int m = m0 + (tm << 2) + i;
    const int c0 = n0 + (tn << 2);
    float4 o0, o1;
    o0.x = acc[i][0]; o0.y = acc[i][1]; o0.z = acc[i][2]; o0.w = acc[i][3];
    o1.x = acc[i][4]; o1.y = acc[i][5]; o1.z = acc[i][6]; o1.w = acc[i][7];
    if (bp) {
      o0.x += bp[c0 + 0]; o0.y += bp[c0 + 1]; o0.z += bp[c0 + 2]; o0.w += bp[c0 + 3];
      o1.x += bp[c0 + 64]; o1.y += bp[c0 + 65]; o1.z += bp[c0 + 66]; o1.w += bp[c0 + 67];
    }
    *reinterpret_cast<float4*>(&Op[(size_t)m * C_DIM + c0]) = o0;
    *reinterpret_cast<float4*>(&Op[(size_t)m * C_DIM + c0 + 64]) = o1;
  }
}

// ---------- hv GEMM: 64x64 tiles, 768 blocks (round-2 proven form) -----------------
__global__ __launch_bounds__(256) void gemm384_kernel(
    const float* __restrict__ A, const float* __restrict__ W,
    const float* __restrict__ bias, float* __restrict__ Out) {
  __shared__ float As[32][64];
  __shared__ float Bs[32][64];
  const int bm = blockIdx.y * 64;
  const int bn = blockIdx.x * 64;
  const int tid = threadIdx.x;
  const int tx = tid & 15;
  const int ty = tid >> 4;
  const int arow = tid >> 3;
  const int akc  = (tid & 7) << 2;
  const int brow = tid >> 4;
  const int bnc  = (tid & 15) << 2;
  float acc[4][4] = {{0.f, 0.f, 0.f, 0.f}, {0.f, 0.f, 0.f, 0.f},
                     {0.f, 0.f, 0.f, 0.f}, {0.f, 0.f, 0.f, 0.f}};
  for (int k0 = 0; k0 < C_DIM; k0 += 32) {
#pragma unroll
    for (int h = 0; h < 2; ++h) {
      float4 a4 = *reinterpret_cast<const float4*>(
          &A[(size_t)(bm + arow + h * 32) * C_DIM + k0 + akc]);
      As[akc + 0][arow + h * 32] = a4.x;
      As[akc + 1][arow + h * 32] = a4.y;
      As[akc + 2][arow + h * 32] = a4.z;
      As[akc + 3][arow + h * 32] = a4.w;
      float4 b4 = *reinterpret_cast<const float4*>(
          &W[(size_t)(k0 + brow + h * 16) * C_DIM + bn + bnc]);
      *reinterpret_cast<float4*>(&Bs[brow + h * 16][bnc]) = b4;
    }
    __syncthreads();
#pragma unroll
    for (int k = 0; k < 32; ++k) {
      float4 a4 = *reinterpret_cast<const float4*>(&As[k][ty << 2]);
      float4 b4 = *reinterpret_cast<const float4*>(&Bs[k][tx << 2]);
      float av[4] = {a4.x, a4.y, a4.z, a4.w};
      float bw[4] = {b4.x, b4.y, b4.z, b4.w};
#pragma unroll
      for (int i = 0; i < 4; ++i)
#pragma unroll
        for (int j = 0; j < 4; ++j) acc[i][j] = fmaf(av[i], bw[j], acc[i][j]);
    }
    __syncthreads();
  }
#pragma unroll
  for (int i = 0; i < 4; ++i) {
    const int m = bm + (ty << 2) + i;
    const int n0 = bn + (tx << 2);
    float4 o;
    o.x = acc[i][0]; o.y = acc[i][1]; o.z = acc[i][2]; o.w = acc[i][3];
    if (bias) {
      o.x += bias[n0 + 0]; o.y += bias[n0 + 1];
      o.z += bias[n0 + 2]; o.w += bias[n0 + 3];
    }
    *reinterpret_cast<float4*>(&Out[(size_t)m * C_DIM + n0]) = o;
  }
}

// ------------- kNN: one wave per query, exact lexicographic (d, idx) top-10 -------
__global__ __launch_bounds__(256) void knn_wave_kernel(
    const float* __restrict__ q_pos, int* __restrict__ idx_out,
    float* __restrict__ scale_out) {
  const int wid = threadIdx.x >> 6;
  const int lane = threadIdx.x & 63;
  const int q = blockIdx.x * 4 + wid;
  const int b = q >> 11;
  const int qi = q & 2047;
  __shared__ float4 sc[N_PTS];
  const float* P = q_pos + (size_t)b * N_PTS * 3;
  for (int i = threadIdx.x; i < N_PTS; i += 256) {
    float x = P[i * 3 + 0], y = P[i * 3 + 1], z = P[i * 3 + 2];
    float s = __fadd_rn(__fadd_rn(__fmul_rn(x, x), __fmul_rn(y, y)), __fmul_rn(z, z));
    sc[i] = make_float4(x, y, z, s);
  }
  __syncthreads();
  const float4 qc = sc[qi];
  unsigned long long bd[K_NN];
#pragma unroll
  for (int t = 0; t < K_NN; ++t) bd[t] = ~0ull;
  for (int t = 0; t < N_PTS / 64; ++t) {
    const int j = (t << 6) + lane;
    float4 c = sc[j];
    float dot = __fadd_rn(__fadd_rn(__fmul_rn(qc.x, c.x), __fmul_rn(qc.y, c.y)),
                          __fmul_rn(qc.z, c.z));
    float d = __fadd_rn(__fadd_rn(__fmul_rn(-2.f, dot), qc.w), c.w);
    unsigned int db = __float_as_uint(d);
    db ^= (unsigned int)((int)db >> 31) | 0x80000000u;
    unsigned long long v = ((unsigned long long)db << 32) | (unsigned int)j;
    if (v < bd[K_NN - 1]) {
#pragma unroll
      for (int r = 0; r < K_NN; ++r) {
        bool lt = bd[r] < v;
        unsigned long long lo = lt ? bd[r] : v;
        unsigned long long hi = lt ? v : bd[r];
        bd[r] = lo; v = hi;
      }
    }
  }
  unsigned long long cur = bd[0];
  unsigned long long mine = 0;
#pragma unroll
  for (int r = 0; r < K_NN; ++r) {
    unsigned long long m = cur;
#pragma unroll
    for (int off = 32; off >= 1; off >>= 1) {
      unsigned long long o = shfl_xor_u64(m, off);
      m = (o < m) ? o : m;
    }
    if (cur == m) {
      cur = bd[1];
#pragma unroll
      for (int s = 1; s < K_NN - 1; ++s) bd[s] = bd[s + 1];
      bd[K_NN - 1] = ~0ull;
    }
    if (lane == r) mine = m;
  }
  const int nidx = (int)(mine & 0xFFFFFFFFull);
  if (lane < K_NN) idx_out[(size_t)q * K_NN + lane] = nidx;
  float mnx, mny, mnz, mxx, mxy, mxz;
  if (lane < K_NN) {
    float4 c = sc[nidx];
    mnx = c.x; mny = c.y; mnz = c.z; mxx = c.x; mxy = c.y; mxz = c.z;
  } else {
    mnx = 1e30f; mny = 1e30f; mnz = 1e30f;
    mxx = -1e30f; mxy = -1e30f; mxz = -1e30f;
  }
#pragma unroll
  for (int off = 32; off >= 1; off >>= 1) {
    mnx = fminf(mnx, __shfl_xor(mnx, off, 64));
    mny = fminf(mny, __shfl_xor(mny, off, 64));
    mnz = fminf(mnz, __shfl_xor(mnz, off, 64));
    mxx = fmaxf(mxx, __shfl_xor(mxx, off, 64));
    mxy = fmaxf(mxy, __shfl_xor(mxy, off, 64));
    mxz = fmaxf(mxz, __shfl_xor(mxz, off, 64));
  }
  if (lane == 0) {
    scale_out[(size_t)q * 3 + 0] = (mxx - mnx) * 0.5f;
    scale_out[(size_t)q * 3 + 1] = (mxy - mny) * 0.5f;
    scale_out[(size_t)q * 3 + 2] = (mxz - mnz) * 0.5f;
  }
}

// -------- per (b,n,k): h=hv[g]+hq -> LN -> GELU -> @W2 -> tanh -> shift_pos --------
__global__ __launch_bounds__(256) void mid_kernel(
    const float* __restrict__ hv, const float* __restrict__ hq,
    const int* __restrict__ idx, const float* __restrict__ scale,
    const float* __restrict__ q_pos, const float* __restrict__ ln_g,
    const float* __restrict__ ln_b, const float* __restrict__ W2,
    float* __restrict__ shift_pos) {
  const int wid = threadIdx.x >> 6;
  const int lane = threadIdx.x & 63;
  const long row = (long)blockIdx.x * 4 + wid;
  const long bn = row / K_NN;
  const int b = (int)(bn / N_PTS);
  const int g = idx[row];
  const float* hvp = hv + ((size_t)b * N_PTS + g) * C_DIM;
  const float* hqp = hq + (size_t)bn * C_DIM;
  float h[6];
  float s = 0.f;
#pragma unroll
  for (int r = 0; r < 6; ++r) {
    h[r] = hvp[lane + (r << 6)] + hqp[lane + (r << 6)];
    s += h[r];
  }
  s = wave_sum64(s);
  const float mu = s / 384.f;
  float hc[6];
  float vs = 0.f;
#pragma unroll
  for (int r = 0; r < 6; ++r) { hc[r] = h[r] - mu; vs += hc[r] * hc[r]; }
  vs = wave_sum64(vs);
  const float inv = 1.f / sqrtf(vs / 384.f + LN_EPS_F);
  float o0 = 0.f, o1 = 0.f, o2 = 0.f;
#pragma unroll
  for (int r = 0; r < 6; ++r) {
    const int c = lane + (r << 6);
    float y = hc[r] * inv * ln_g[c] + ln_b[c];
    float ge = 0.5f * y * (1.f + erff(y * 0.70710678118654752f));
    o0 += ge * W2[c * 3 + 0];
    o1 += ge * W2[c * 3 + 1];
    o2 += ge * W2[c * 3 + 2];
  }
  o0 = wave_sum64(o0); o1 = wave_sum64(o1); o2 = wave_sum64(o2);
  if (lane < 3) {
    float o = (lane == 0) ? o0 : ((lane == 1) ? o1 : o2);
    float off = tanhf(o);
    float lv = q_pos[((size_t)b * N_PTS + g) * 3 + lane];
    float sc = scale[(size_t)bn * 3 + lane];
    shift_pos[(size_t)row * 3 + lane] = lv + off * sc;
  }
}

// ------------- three_nn phase A: per candidate-chunk top-3 partials ---------------
__global__ __launch_bounds__(256) void three_nn_part_kernel(
    const float* __restrict__ shift_pos, const float* __restrict__ q_pos,
    float* __restrict__ pd3, int* __restrict__ pi3) {
  const int cc = blockIdx.x;
  const int qc = blockIdx.y;
  const int b = qc / (NK / 256);
  const float* P = q_pos + (size_t)b * N_PTS * 3;
  __shared__ float4 sc[TCHUNK];
  const int c0 = cc * TCHUNK;
  for (int i = threadIdx.x; i < TCHUNK; i += 256) {
    float x = P[(c0 + i) * 3 + 0], y = P[(c0 + i) * 3 + 1], z = P[(c0 + i) * 3 + 2];
    float s = __fadd_rn(__fadd_rn(__fmul_rn(x, x), __fmul_rn(y, y)), __fmul_rn(z, z));
    sc[i] = make_float4(x, y, z, s);
  }
  __syncthreads();
  const long jq = (long)qc * 256 + threadIdx.x;
  const float* S = shift_pos + (size_t)jq * 3;
  const float px = S[0], py = S[1], pz = S[2];
  const float ps = __fadd_rn(__fadd_rn(__fmul_rn(px, px), __fmul_rn(py, py)),
                             __fmul_rn(pz, pz));
  float d0 = 1e30f, d1 = 1e30f, d2 = 1e30f;
  int i0 = 0, i1 = 0, i2 = 0;
  for (int j = 0; j < TCHUNK; ++j) {
    float4 c = sc[j];
    float dot = __fadd_rn(__fadd_rn(__fmul_rn(px, c.x), __fmul_rn(py, c.y)),
                          __fmul_rn(pz, c.z));
    float d = __fadd_rn(__fadd_rn(__fmul_rn(-2.f, dot), ps), c.w);
    if (d < d2) {
      int j0 = c0 + j;
      if (d < d0)      { d2 = d1; i2 = i1; d1 = d0; i1 = i0; d0 = d; i0 = j0; }
      else if (d < d1) { d2 = d1; i2 = i1; d1 = d; i1 = j0; }
      else             { d2 = d; i2 = j0; }
    }
  }
  const size_t base = ((size_t)jq * TCC + cc) * 3;
  pd3[base + 0] = d0; pd3[base + 1] = d1; pd3[base + 2] = d2;
  pi3[base + 0] = i0; pi3[base + 1] = i1; pi3[base + 2] = i2;
}

// ------------- three_nn phase B: merge TCC top-3 lists -> weights -----------------
__global__ __launch_bounds__(256) void three_nn_merge_kernel(
    const float* __restrict__ pd3, const int* __restrict__ pi3,
    int* __restrict__ idx3, float* __restrict__ w3) {
  const long jq = (long)blockIdx.x * 256 + threadIdx.x;
  float d0 = 1e30f, d1 = 1e30f, d2 = 1e30f;
  int i0 = 0, i1 = 0, i2 = 0;
  const size_t base = (size_t)jq * TCC * 3;
  for (int e = 0; e < TCC * 3; ++e) {
    float d = pd3[base + e];
    if (d < d2) {
      int j0 = pi3[base + e];
      if (d < d0)      { d2 = d1; i2 = i1; d1 = d0; i1 = i0; d0 = d; i0 = j0; }
      else if (d < d1) { d2 = d1; i2 = i1; d1 = d; i1 = j0; }
      else             { d2 = d; i2 = j0; }
    }
  }
  const float r0 = 1.f / (d0 + 1e-8f);
  const float r1 = 1.f / (d1 + 1e-8f);
  const float r2 = 1.f / (d2 + 1e-8f);
  const float rs = (r0 + r1) + r2;
  const size_t ob = (size_t)jq * 3;
  idx3[ob + 0] = i0; idx3[ob + 1] = i1; idx3[ob + 2] = i2;
  w3[ob + 0] = r0 / rs; w3[ob + 1] = r1 / rs; w3[ob + 2] = r2 / rs;
}

// -------- final: out[bn,c] = max_k leaky( sum_i w_i*qa[idx3_i,c] + qb-qa ) --------
__global__ __launch_bounds__(256) void final_kernel(
    const float* __restrict__ qa, const float* __restrict__ qb,
    const int* __restrict__ idx3, const float* __restrict__ w3,
    float* __restrict__ out) {
  const int wid = threadIdx.x >> 6;
  const int lane = threadIdx.x & 63;
  const long bn = (long)blockIdx.x * 4 + wid;
  const int b = (int)(bn / N_PTS);
  const float* qaB = qa + (size_t)b * N_PTS * C_DIM;
  float base[6], mx[6];
#pragma unroll
  for (int r = 0; r < 6; ++r) {
    const size_t c = (size_t)bn * C_DIM + lane + (r << 6);
    base[r] = qb[c] - qa[c];
    mx[r] = -1e30f;
  }
  const size_t kb = (size_t)bn * K_NN * 3;
  for (int k = 0; k < K_NN; ++k) {
    const int a0 = idx3[kb + k * 3 + 0];
    const int a1 = idx3[kb + k * 3 + 1];
    const int a2 = idx3[kb + k * 3 + 2];
    const float w0 = w3[kb + k * 3 + 0];
    const float w1 = w3[kb + k * 3 + 1];
    const float w2c = w3[kb + k * 3 + 2];
    const float* p0 = qaB + (size_t)a0 * C_DIM;
    const float* p1 = qaB + (size_t)a1 * C_DIM;
    const float* p2 = qaB + (size_t)a2 * C_DIM;
#pragma unroll
    for (int r = 0; r < 6; ++r) {
      const int c = lane + (r << 6);
      float v = w0 * p0[c] + w1 * p1[c] + w2c * p2[c] + base[r];
      v = (v >= 0.f) ? v : 0.2f * v;
      mx[r] = fmaxf(mx[r], v);
    }
  }
#pragma unroll
  for (int r = 0; r < 6; ++r)
    out[(size_t)bn * C_DIM + lane + (r << 6)] = mx[r];
}

extern "C" void kernel_launch(void* const* d_in, const int* in_sizes, int n_in,
                              void* d_out, int out_size, void* d_ws, size_t ws_size,
                              hipStream_t stream) {
  const float* q     = (const float*)d_in[0];
  const float* q_pos = (const float*)d_in[1];
  const float* Wv    = (const float*)d_in[2];
  const float* bv    = (const float*)d_in[3];
  const float* W1    = (const float*)d_in[4];
  const float* b1    = (const float*)d_in[5];
  const float* ln_g  = (const float*)d_in[6];
  const float* ln_b  = (const float*)d_in[7];
  const float* W2    = (const float*)d_in[8];
  const float* Wk    = (const float*)d_in[9];
  const float* bk    = (const float*)d_in[10];
  float* out = (float*)d_out;

  const int BN = in_sizes[0] / C_DIM;  // B*N = 8192

  const size_t BNC = (size_t)BN * C_DIM;
  float* ws = (float*)d_ws;
  float* bufA = ws;              // qa
  float* bufB = bufA + BNC;      // qbf -> hv -> pd3
  float* bufC = bufB + BNC;      // WkT -> hq -> pi3
  float* bufD = bufC + BNC;      // qb
  float* shift = bufD + BNC;                       // BN*K*3
  float* scale = shift + (size_t)BN * K_NN * 3;    // BN*3
  float* w3    = scale + (size_t)BN * 3;           // BN*K*3
  int*   idx   = (int*)(w3 + (size_t)BN * K_NN * 3);  // BN*K
  int*   idx3  = idx + (size_t)BN * K_NN;             // BN*K*3

  float* v_off = out;            // d_out staging: dead until final_kernel rewrites it
  unsigned short* qbf = (unsigned short*)bufB;   // 8192x384 bf16
  unsigned short* WkT = (unsigned short*)bufC;   // 768x384 bf16
  float* pd3 = bufB;
  int*   pi3 = (int*)bufC;

  // 1) conversions (value-only path inputs)
  conv_q_kernel<<<(BN * C_DIM) / 1024, 256, 0, stream>>>(q, qbf);
  conv_wkT_kernel<<<dim3(6, 12), 256, 0, stream>>>(Wk, WkT);
  // 2) kNN (wave per query) -> idx, scale
  knn_wave_kernel<<<BN / 4, 256, 0, stream>>>(q_pos, idx, scale);
  // 3) MFMA bf16: qa = q@Wka ; qb = q@Wkb + bk
  mfma_qaqb_kernel<<<dim3(12, BN / 64), 64, 0, stream>>>(qbf, WkT, bk, bufA, bufD);
  // 4) f32 exact: v_off = q@Wv+bv (d_out) ; hq = q@W1b+b1 (bufC, overwrites WkT)
  sgemm_q2_kernel<<<dim3(6, BN / 64), 256, 0, stream>>>(
      q, Wv, W1 + (size_t)C_DIM * C_DIM, bv, b1, v_off, bufC);
  // 5) hv = v_off @ W1a (bufB, overwrites qbf)
  gemm384_kernel<<<dim3(C_DIM / 64, BN / 64), 256, 0, stream>>>(v_off, W1, nullptr, bufB);
  // 6) mid: LN/GELU/W2/tanh -> shift_pos
  mid_kernel<<<(BN * K_NN) / 4, 256, 0, stream>>>(bufB, bufC, idx, scale, q_pos,
                                                  ln_g, ln_b, W2, shift);
  // 7-8) three_nn (dense lockstep brute force — proven VALU-issue-bound form)
  three_nn_part_kernel<<<dim3(TCC, (BN * K_NN) / 256), 256, 0, stream>>>(
      shift, q_pos, pd3, pi3);
  three_nn_merge_kernel<<<(BN * K_NN) / 256, 256, 0, stream>>>(pd3, pi3, idx3, w3);
  // 9) final gather + leaky + max
  final_kernel<<<BN / 4, 256, 0, stream>>>(bufA, bufD, idx3, w3, out);
}